// Round 1
// baseline (9809.283 us; speedup 1.0000x reference)
//
#include <hip/hip_runtime.h>
#include <hip/hip_bf16.h>

// RNN_73418170958322 on MI355X — R2
// out[t] = h_{t+1} @ Wo^T + bo,  h_{t+1} = tanh(EW[x[t]] + h_t @ Wh^T + bh),
// EW = emb @ Wi^T + bi  (V=512 rows -> precompute).
//
// Persistent kernel: 256 blocks x 256 thr. Block(g=blk&7,c=blk>>3): batches [16g,16g+16),
// h-cols [64c,64c+64), o-cols [16c,16c+16). Wh B-frags in VGPRs (256/wave), Wo K-slice too.
//
// R2 theory: step time is MALL *request-rate* bound (2.1M sc1 8B atomic loads + 262K 2B
// sc1 stores per step ~= 256K req/us observed). Two changes:
//  (a) FULL-HISTORY h buffer (1025 slots, never-reused addresses) => consumers use PLAIN
//      cached dwordx4 loads. Producers still publish sc1 (write-through to memory-side
//      MALL); a fresh address can never be stale in any L1/L2, and each 128B line is
//      written entirely by one block (64-col ranges are line-aligned). Per-XCD L2 absorbs
//      the 32x read amplification (group g=blk&7 ~ one XCD under round-robin; perf-only
//      assumption, correctness holds for any mapping). Gated on ws_size; otherwise exact
//      R1 ping-pong sc1 fallback.
//  (b) h store via 2KB LDS transpose: one u64 sc1 store/thread instead of 4 scattered 2B
//      stores (262K -> 65K requests, shorter drain). Costs one extra __syncthreads.
// LDS staging keeps the verified XOR swizzle layout: u64 unit u of row sr lives at
// (c4<<8) + ((sr^(c4&15))<<4) + (hf<<3), c4=u>>1, hf=u&1.

#define T_DIM 1024
#define B_DIM 128
#define V_DIM 512
#define H_DIM 2048
#define O_DIM 512

typedef __attribute__((ext_vector_type(4))) float f32x4;
typedef __attribute__((ext_vector_type(8))) short s16x8;
typedef unsigned long long u64;

// workspace layout (bytes)
#define WS_WHB   0u          // bf16 Wh      [2048,2048]  8 MB
#define WS_WOB   8388608u    // bf16 Wo      [512,2048]   2 MB
#define WS_EMBB  10485760u   // bf16 emb     [512,512]    512 KB
#define WS_WIB   11010048u   // bf16 Wi      [2048,512]   2 MB
#define WS_EW    13107200u   // f32  EW      [512,2048]   4 MB
#define WS_BAR   17301504u   // int  barrier counters, 8 groups x 128B (1 KB)
#define WS_HBUF  17302528u   // bf16 h slots [nslot][128,2048]; hist: 1025 slots, else 2
#define HBUF_SLOT (B_DIM * H_DIM)  // shorts per slot (512 KB)

__device__ __forceinline__ float tanh_fast(float v) {
  v = fminf(15.0f, fmaxf(-15.0f, v));
  float e = __expf(2.0f * v);
  return (e - 1.0f) / (e + 1.0f);
}

__global__ __launch_bounds__(256) void cast_bf16_kernel(const float* __restrict__ src,
                                                        __hip_bfloat16* __restrict__ dst,
                                                        int n8) {
  int idx = blockIdx.x * 256 + threadIdx.x;
  if (idx >= n8) return;
  const f32x4* s4 = (const f32x4*)src;
  f32x4 a = s4[idx * 2], b = s4[idx * 2 + 1];
  short o[8];
#pragma unroll
  for (int j = 0; j < 4; ++j) {
    __hip_bfloat16 t1 = __float2bfloat16(a[j]);
    __hip_bfloat16 t2 = __float2bfloat16(b[j]);
    o[j] = __builtin_bit_cast(short, t1);
    o[j + 4] = __builtin_bit_cast(short, t2);
  }
  s16x8 v = {o[0], o[1], o[2], o[3], o[4], o[5], o[6], o[7]};
  ((s16x8*)dst)[idx] = v;
}

// EW[v,j] = sum_u emb[v,u]*Wi[j,u] + bi[j]. One 16x16 tile per wave. M=512,N=2048,K=512.
__global__ __launch_bounds__(256) void ew_kernel(const __hip_bfloat16* __restrict__ embb,
                                                 const __hip_bfloat16* __restrict__ Wib,
                                                 const float* __restrict__ bi,
                                                 float* __restrict__ EW,
                                                 int* __restrict__ bar) {
  if (blockIdx.x == 0) {
    __hip_atomic_store(bar + threadIdx.x, 0, __ATOMIC_RELAXED, __HIP_MEMORY_SCOPE_AGENT);
  }
  int wid = blockIdx.x * 4 + (threadIdx.x >> 6);
  int lane = threadIdx.x & 63;
  int mt = wid >> 7;    // 0..31
  int nt = wid & 127;   // 0..127
  int m16 = lane & 15, q = lane >> 4;
  const s16x8* arow = (const s16x8*)(embb + (size_t)(mt * 16 + m16) * V_DIM + q * 8);
  const s16x8* brow = (const s16x8*)(Wib + (size_t)(nt * 16 + m16) * V_DIM + q * 8);
  f32x4 acc = {0, 0, 0, 0};
#pragma unroll
  for (int kk = 0; kk < 16; ++kk) {
    s16x8 af = arow[kk * 4];
    s16x8 bf = brow[kk * 4];
    acc = __builtin_amdgcn_mfma_f32_16x16x32_bf16(af, bf, acc, 0, 0, 0);
  }
  float biv = bi[nt * 16 + m16];
#pragma unroll
  for (int ii = 0; ii < 4; ++ii)
    EW[(size_t)(mt * 16 + q * 4 + ii) * H_DIM + nt * 16 + m16] = acc[ii] + biv;
}

__global__ __launch_bounds__(256, 1) void rnn_persistent(
    const int* __restrict__ x, const float* __restrict__ EW,
    const __hip_bfloat16* __restrict__ Whb, const __hip_bfloat16* __restrict__ Wob,
    const float* __restrict__ bh, const float* __restrict__ bo,
    unsigned short* __restrict__ hbuf, int* __restrict__ bar, float* __restrict__ out,
    int hist) {
  extern __shared__ char smem[];
  float* o_red = (float*)smem;                                // 4 KB, aliases A-stage
  unsigned short* h_stage = (unsigned short*)(smem + 4096);   // 2 KB, aliases A-stage

  const int tid = threadIdx.x;
  const int lane = tid & 63;
  const int w = tid >> 6;            // wave 0..3
  const int g = blockIdx.x & 7;      // batch group
  const int c = blockIdx.x >> 3;     // col group 0..31
  const int b0 = g << 4;
  const int hcol0 = c << 6;
  const int ocol0 = c << 4;
  const int m16 = lane & 15;
  const int q = lane >> 4;

  // one-time: Wh B-fragments for this wave's 16 h-cols, all K=2048 -> 64 frags in VGPRs
  s16x8 bf_h[64];
  {
    const s16x8* wrow =
        (const s16x8*)(Whb + (size_t)(hcol0 + (w << 4) + m16) * H_DIM + q * 8);
#pragma unroll
    for (int kk = 0; kk < 64; ++kk) bf_h[kk] = wrow[kk * 4];
  }
  // one-time: Wo B-fragments for this wave's K-slice [512w, 512w+512)
  s16x8 bf_o[16];
  {
    const s16x8* orow =
        (const s16x8*)(Wob + (size_t)(ocol0 + m16) * H_DIM + (w << 9) + q * 8);
#pragma unroll
    for (int kk = 0; kk < 16; ++kk) bf_o[kk] = orow[kk * 4];
  }
  const float bh_v = bh[hcol0 + (w << 4) + m16];
  const float bo_v = bo[ocol0 + (tid & 15)];

  int* bar_g = bar + g * 32;  // 128B-padded counter per group

  const int sr = tid >> 4;  // staging row 0..15
  const int sc = tid & 15;  // staging lane-within-row 0..15

  for (int i = 0; i <= T_DIM; ++i) {
    const size_t rd_off = (hist ? (size_t)i : (size_t)(i & 1)) * (size_t)HBUF_SLOT;
    const size_t wr_off = (hist ? (size_t)(i + 1) : (size_t)((i + 1) & 1)) * (size_t)HBUF_SLOT;

    // wait until all 32 blocks of the group published s_i (one relaxed add each per step)
    if (i > 0 && tid == 0) {
      const int target = i << 5;
      while (__hip_atomic_load(bar_g, __ATOMIC_RELAXED, __HIP_MEMORY_SCOPE_AGENT) < target) {
        __builtin_amdgcn_s_sleep(1);
      }
    }
    __syncthreads();

    // prefetch this step's embedding-projection values (independent of h_t; L2-warm)
    float ew_pre[4];
    if (i < T_DIM) {
      const int n = hcol0 + (w << 4) + m16;
#pragma unroll
      for (int ii = 0; ii < 4; ++ii) {
        int b = b0 + (q << 2) + ii;
        int xv = x[i * B_DIM + b];
        ew_pre[ii] = EW[(size_t)xv * H_DIM + n];
      }
    }

    // stage s_i[b0..b0+16, :] -> LDS, XOR-swizzled [chunk(16B)][row^(chunk&15)][16B]
    if (i == 0) {
#pragma unroll
      for (int j = 0; j < 32; ++j) *(u64*)(smem + (tid << 8) + (j << 3)) = 0ull;
    } else if (hist) {
      // plain cached 16B loads from the never-reused history slot
      const unsigned short* rbase = hbuf + rd_off + (size_t)(b0 + sr) * H_DIM;
#pragma unroll
      for (int half = 0; half < 2; ++half) {
        s16x8 v[8];
#pragma unroll
        for (int j = 0; j < 8; ++j) {
          int c4 = sc + (((half << 3) + j) << 4);
          v[j] = *(const s16x8*)(rbase + (c4 << 3));
        }
#pragma unroll
        for (int j = 0; j < 8; ++j) {
          int c4 = sc + (((half << 3) + j) << 4);
          int rp = sr ^ (c4 & 15);
          char* d = smem + (c4 << 8) + (rp << 4);
          *(u64*)d = ((const u64*)&v[j])[0];
          *(u64*)(d + 8) = ((const u64*)&v[j])[1];
        }
      }
    } else {
      // fallback: proven sc1 atomic-load path (ping-pong slots)
      const u64* hsrc = (const u64*)(hbuf + rd_off + (size_t)(b0 + sr) * H_DIM);
#pragma unroll
      for (int half = 0; half < 2; ++half) {
        u64 v[16];
#pragma unroll
        for (int j = 0; j < 16; ++j) {
          int u = sc + (((half << 4) + j) << 4);
          v[j] = __hip_atomic_load((u64*)(hsrc + u), __ATOMIC_RELAXED,
                                   __HIP_MEMORY_SCOPE_AGENT);
        }
#pragma unroll
        for (int j = 0; j < 16; ++j) {
          int u = sc + (((half << 4) + j) << 4);
          int c4 = u >> 1, hf = u & 1;
          int rp = sr ^ (c4 & 15);
          *(u64*)(smem + (c4 << 8) + (rp << 4) + (hf << 3)) = v[j];
        }
      }
    }
    __syncthreads();

    f32x4 acc[4], acco[2];
#pragma unroll
    for (int j = 0; j < 4; ++j) acc[j] = (f32x4){0, 0, 0, 0};
    acco[0] = (f32x4){0, 0, 0, 0};
    acco[1] = (f32x4){0, 0, 0, 0};

#pragma unroll
    for (int kk = 0; kk < 64; ++kk) {
      int c4 = (kk << 2) + q;
      s16x8 af = *(const s16x8*)(smem + (c4 << 8) + ((m16 ^ (c4 & 15)) << 4));
      acc[kk & 3] = __builtin_amdgcn_mfma_f32_16x16x32_bf16(af, bf_h[kk], acc[kk & 3], 0, 0, 0);
      int ko = kk - (w << 4);
      if ((unsigned)ko < 16u)  // this wave's o K-slice reuses the same A-frag
        acco[ko & 1] = __builtin_amdgcn_mfma_f32_16x16x32_bf16(af, bf_o[ko], acco[ko & 1], 0, 0, 0);
    }

    // h_{i+1} = tanh(EW[x_i] + acc + bh) -> registers
    float th4[4];
    const bool wr = (i < T_DIM);
    if (wr) {
      f32x4 a = (acc[0] + acc[1]) + (acc[2] + acc[3]);
      const int n = hcol0 + (w << 4) + m16;
#pragma unroll
      for (int ii = 0; ii < 4; ++ii) {
        float pre = ew_pre[ii] + bh_v + a[ii];
        th4[ii] = tanh_fast(pre);
        if (i == T_DIM - 1)  // final hidden state, f32, appended after out
          out[(size_t)T_DIM * B_DIM * O_DIM + (size_t)(b0 + (q << 2) + ii) * H_DIM + n] =
              th4[ii];
      }
    }

    __syncthreads();  // sync(A): all A-frag LDS reads done -> h_stage/o_red may alias

    if (wr) {  // transpose h through LDS so each thread emits ONE u64 sc1 store
#pragma unroll
      for (int ii = 0; ii < 4; ++ii) {
        int bl = (q << 2) + ii;
        h_stage[bl * 64 + (w << 4) + m16] =
            __builtin_bit_cast(unsigned short, __float2bfloat16(th4[ii]));
      }
    }
    if (i > 0) {
      f32x4 ao = acco[0] + acco[1];
#pragma unroll
      for (int ii = 0; ii < 4; ++ii)
        o_red[(w << 8) + ((q << 2) + ii) * 16 + m16] = ao[ii];
    }
    __syncthreads();  // sync(B): h_stage + o_red ready

    if (wr) {
      u64 hv = *(const u64*)(h_stage + (tid << 2));  // [b=tid>>4][u64 unit=tid&15]
      unsigned short* wbase =
          hbuf + wr_off + (size_t)(b0 + sr) * H_DIM + hcol0 + (sc << 2);
      __hip_atomic_store((u64*)wbase, hv, __ATOMIC_RELAXED, __HIP_MEMORY_SCOPE_AGENT);
    }
    float ov = 0.0f;
    if (i > 0)
      ov = o_red[tid] + o_red[256 + tid] + o_red[512 + tid] + o_red[768 + tid] + bo_v;

    // every thread drains its device-scope h store, block-barrier, then one signal.
    __builtin_amdgcn_s_waitcnt(0);
    __syncthreads();  // sync(C)

    if (wr && tid == 0) {
      __hip_atomic_fetch_add(bar_g, 1, __ATOMIC_RELAXED, __HIP_MEMORY_SCOPE_AGENT);
    }
    if (i > 0) {  // out[i-1] = sum of 4 wave partials + bo
      out[(size_t)(i - 1) * (B_DIM * O_DIM) + (size_t)(b0 + (tid >> 4)) * O_DIM + ocol0 +
          (tid & 15)] = ov;
    }
  }
}

extern "C" void kernel_launch(void* const* d_in, const int* in_sizes, int n_in,
                              void* d_out, int out_size, void* d_ws, size_t ws_size,
                              hipStream_t stream) {
  const int* x = (const int*)d_in[0];
  const float* emb = (const float*)d_in[1];
  const float* Wi = (const float*)d_in[2];
  const float* bi = (const float*)d_in[3];
  const float* Wh = (const float*)d_in[4];
  const float* bh = (const float*)d_in[5];
  const float* Wo = (const float*)d_in[6];
  const float* bo = (const float*)d_in[7];
  float* out = (float*)d_out;
  char* ws = (char*)d_ws;

  __hip_bfloat16* Whb = (__hip_bfloat16*)(ws + WS_WHB);
  __hip_bfloat16* Wob = (__hip_bfloat16*)(ws + WS_WOB);
  __hip_bfloat16* embb = (__hip_bfloat16*)(ws + WS_EMBB);
  __hip_bfloat16* Wib = (__hip_bfloat16*)(ws + WS_WIB);
  float* EW = (float*)(ws + WS_EW);
  int* bar = (int*)(ws + WS_BAR);
  unsigned short* hbuf = (unsigned short*)(ws + WS_HBUF);

  // full history needs 1025 slots x 512 KB after WS_HBUF
  const size_t hist_need =
      (size_t)WS_HBUF + 1025ull * (size_t)HBUF_SLOT * sizeof(unsigned short);
  const int hist = (ws_size >= hist_need) ? 1 : 0;

  hipMemsetAsync(ws + WS_BAR, 0, 1024, stream);

  cast_bf16_kernel<<<2048, 256, 0, stream>>>(Wh, Whb, 524288);
  cast_bf16_kernel<<<512, 256, 0, stream>>>(Wo, Wob, 131072);
  cast_bf16_kernel<<<128, 256, 0, stream>>>(emb, embb, 32768);
  cast_bf16_kernel<<<512, 256, 0, stream>>>(Wi, Wib, 131072);
  ew_kernel<<<1024, 256, 0, stream>>>(embb, Wib, bi, EW, bar);
  rnn_persistent<<<256, 256, 65536, stream>>>(x, EW, Whb, Wob, bh, bo, hbuf, bar, out,
                                              hist);
}